// Round 1
// baseline (930.742 us; speedup 1.0000x reference)
//
#include <hip/hip_runtime.h>
#include <hip/hip_bf16.h>

typedef __bf16 bf16_t;
typedef __bf16 bf16x4 __attribute__((ext_vector_type(4)));
typedef __bf16 bf16x8 __attribute__((ext_vector_type(8)));
typedef float f32x4 __attribute__((ext_vector_type(4)));

// Problem dims (fixed): B=8, S=512, D=1024, H=16, DK=64; M=B*S=4096, N=K=1024.

__device__ __forceinline__ f32x4 mfma16(bf16x8 a, bf16x8 b, f32x4 c) {
    return __builtin_amdgcn_mfma_f32_16x16x32_bf16(a, b, c, 0, 0, 0);
}

// ---------- prep: fp32 -> bf16 cast (x) ----------
__global__ __launch_bounds__(256) void cast_kernel(const float* __restrict__ x,
                                                   bf16_t* __restrict__ xb) {
    size_t i = ((size_t)blockIdx.x * 256 + threadIdx.x) * 4;
    float4 v = *(const float4*)(x + i);
    bf16x4 o;
    o[0] = (bf16_t)v.x; o[1] = (bf16_t)v.y; o[2] = (bf16_t)v.z; o[3] = (bf16_t)v.w;
    *(bf16x4*)(xb + i) = o;
}

// ---------- prep: W [K=1024][N=1024] f32 -> Wt [N][K] bf16 ----------
__global__ __launch_bounds__(256) void transpose_kernel(const float* __restrict__ W,
                                                        bf16_t* __restrict__ Wt) {
    __shared__ float tile[32][33];
    int tx = threadIdx.x & 31, ty = threadIdx.x >> 5;  // 32x8
    int bx = blockIdx.x * 32, by = blockIdx.y * 32;    // bx: n, by: k
#pragma unroll
    for (int j = 0; j < 4; j++)
        tile[ty + j * 8][tx] = W[(size_t)(by + ty + j * 8) * 1024 + bx + tx];
    __syncthreads();
#pragma unroll
    for (int j = 0; j < 4; j++)
        Wt[(size_t)(bx + ty + j * 8) * 1024 + by + tx] = (bf16_t)tile[tx][ty + j * 8];
}

// ---------- GEMM: C[m][n] = A[m][:] . Bt[n][:] + bias[n], various epilogues ----------
// MODE 0: write bf16 [B,H,S,DK]   (Q and K layouts)
// MODE 2: write bf16 [B,H,DK,S]   (V transposed for PV mfma B-fragments)
// MODE 3: write f32  [M,N] = v + resid[m][n]   (output proj + residual, pre-LN)
template <int MODE>
__global__ __launch_bounds__(256) void gemm_bt(const bf16_t* __restrict__ A,
                                               const bf16_t* __restrict__ Bt,
                                               const float* __restrict__ bias,
                                               const float* __restrict__ resid,
                                               void* __restrict__ outp) {
    constexpr int K = 1024, N = 1024;
    __shared__ bf16_t As[128][40];  // +8 pad: stride 80B = 20 banks -> 2-way (free)
    __shared__ bf16_t Bs[128][40];
    const int t = threadIdx.x;
    const int lane = t & 63;
    const int wv = t >> 6;
    const int lm = lane & 15, q4 = lane >> 4;
    const int mblk = blockIdx.y * 128, nblk = blockIdx.x * 128;
    const int mrow = (wv & 1) * 64, ncol = (wv >> 1) * 64;

    f32x4 acc[4][4];
#pragma unroll
    for (int r = 0; r < 4; r++)
#pragma unroll
        for (int c = 0; c < 4; c++) acc[r][c] = (f32x4){0.f, 0.f, 0.f, 0.f};

    for (int k0 = 0; k0 < K; k0 += 32) {
#pragma unroll
        for (int ld = 0; ld < 2; ld++) {
            int id = t + ld * 256;
            int r = id >> 2, c = (id & 3) * 8;
            *(bf16x8*)&As[r][c] = *(const bf16x8*)&A[(size_t)(mblk + r) * K + k0 + c];
            *(bf16x8*)&Bs[r][c] = *(const bf16x8*)&Bt[(size_t)(nblk + r) * K + k0 + c];
        }
        __syncthreads();
        bf16x8 af[4], bf[4];
#pragma unroll
        for (int r = 0; r < 4; r++) af[r] = *(const bf16x8*)&As[mrow + r * 16 + lm][q4 * 8];
#pragma unroll
        for (int c = 0; c < 4; c++) bf[c] = *(const bf16x8*)&Bs[ncol + c * 16 + lm][q4 * 8];
#pragma unroll
        for (int r = 0; r < 4; r++)
#pragma unroll
            for (int c = 0; c < 4; c++) acc[r][c] = mfma16(af[r], bf[c], acc[r][c]);
        __syncthreads();
    }

#pragma unroll
    for (int r = 0; r < 4; r++)
#pragma unroll
        for (int c = 0; c < 4; c++)
#pragma unroll
            for (int i = 0; i < 4; i++) {
                int m = mblk + mrow + r * 16 + q4 * 4 + i;
                int n = nblk + ncol + c * 16 + lm;
                float v = acc[r][c][i] + bias[n];
                if (MODE == 0) {
                    int b = m >> 9, s = m & 511, h = n >> 6, d = n & 63;
                    ((bf16_t*)outp)[(((size_t)(b * 16 + h) * 512) + s) * 64 + d] = (bf16_t)v;
                } else if (MODE == 2) {
                    int b = m >> 9, s = m & 511, h = n >> 6, d = n & 63;
                    ((bf16_t*)outp)[(((size_t)(b * 16 + h) * 64) + d) * 512 + s] = (bf16_t)v;
                } else {
                    ((float*)outp)[(size_t)m * N + n] = v + resid[(size_t)m * N + n];
                }
            }
}

// ---------- scores = QK^T/8, attn_mask, help blend, softmax -> attn [B,H,S,S] f32 ----------
__global__ __launch_bounds__(256) void attn_kernel(const bf16_t* __restrict__ Qb,
                                                   const bf16_t* __restrict__ Kb,
                                                   const float* __restrict__ help_vals,
                                                   const int* __restrict__ help_mask,
                                                   const int* __restrict__ attn_mask,
                                                   float* __restrict__ attn_out) {
    const int t = threadIdx.x;
    const int lane = t & 63, wv = t >> 6;
    const int lm = lane & 15, q4 = lane >> 4;
    const int bh = blockIdx.y;
    const int b = bh >> 4;
    const int q0 = blockIdx.x * 64 + wv * 16;  // wave's 16 q rows
    const bf16_t* Qp = Qb + (size_t)bh * 512 * 64;
    const bf16_t* Kp = Kb + (size_t)bh * 512 * 64;

    bf16x8 aq0 = *(const bf16x8*)&Qp[(size_t)(q0 + lm) * 64 + q4 * 8];
    bf16x8 aq1 = *(const bf16x8*)&Qp[(size_t)(q0 + lm) * 64 + 32 + q4 * 8];

    f32x4 acc[32];
#pragma unroll
    for (int kt = 0; kt < 32; kt++) acc[kt] = (f32x4){0.f, 0.f, 0.f, 0.f};
#pragma unroll
    for (int kt = 0; kt < 32; kt++) {
        bf16x8 b0 = *(const bf16x8*)&Kp[(size_t)(kt * 16 + lm) * 64 + q4 * 8];
        bf16x8 b1 = *(const bf16x8*)&Kp[(size_t)(kt * 16 + lm) * 64 + 32 + q4 * 8];
        acc[kt] = mfma16(aq0, b0, acc[kt]);
        acc[kt] = mfma16(aq1, b1, acc[kt]);
    }

    // blend with help scores + attn mask; track row max
    float mrow[4] = {-3e38f, -3e38f, -3e38f, -3e38f};
#pragma unroll
    for (int kt = 0; kt < 32; kt++) {
#pragma unroll
        for (int i = 0; i < 4; i++) {
            int q = q0 + q4 * 4 + i;
            int key = kt * 16 + lm;
            size_t hidx = ((size_t)bh * 512 + q) * 512 + key;
            size_t aidx = ((size_t)b * 512 + q) * 512 + key;
            float s = acc[kt][i] * 0.125f;           // 1/sqrt(64)
            if (attn_mask[aidx]) s = -1e9f;          // masked_fill
            if (help_mask[hidx]) s = 0.5f * help_vals[hidx] + 0.5f * s;  // m=1 blend
            acc[kt][i] = s;
            mrow[i] = fmaxf(mrow[i], s);
        }
    }
#pragma unroll
    for (int i = 0; i < 4; i++) {
#pragma unroll
        for (int off = 1; off < 16; off <<= 1) mrow[i] = fmaxf(mrow[i], __shfl_xor(mrow[i], off));
    }
    float srow[4] = {0.f, 0.f, 0.f, 0.f};
#pragma unroll
    for (int kt = 0; kt < 32; kt++)
#pragma unroll
        for (int i = 0; i < 4; i++) {
            float p = __expf(acc[kt][i] - mrow[i]);
            acc[kt][i] = p;
            srow[i] += p;
        }
#pragma unroll
    for (int i = 0; i < 4; i++) {
#pragma unroll
        for (int off = 1; off < 16; off <<= 1) srow[i] += __shfl_xor(srow[i], off);
        srow[i] = 1.0f / srow[i];
    }
#pragma unroll
    for (int kt = 0; kt < 32; kt++)
#pragma unroll
        for (int i = 0; i < 4; i++) {
            int q = q0 + q4 * 4 + i;
            int key = kt * 16 + lm;
            attn_out[((size_t)bh * 512 + q) * 512 + key] = acc[kt][i] * srow[i];
        }
}

// ---------- ctx = attn @ V  -> xo [B,S,H*DK] bf16 ----------
__global__ __launch_bounds__(256) void pv_kernel(const float* __restrict__ attn,
                                                 const bf16_t* __restrict__ Vt,
                                                 bf16_t* __restrict__ xo) {
    const int t = threadIdx.x;
    const int lane = t & 63, wv = t >> 6;
    const int lm = lane & 15, q4 = lane >> 4;
    const int bh = blockIdx.y;
    const int q0 = blockIdx.x * 64 + wv * 16;
    const float* Pp = attn + (size_t)bh * 512 * 512;
    const bf16_t* Vp = Vt + (size_t)bh * 64 * 512;  // [dk][s]

    f32x4 acc[4];
#pragma unroll
    for (int c = 0; c < 4; c++) acc[c] = (f32x4){0.f, 0.f, 0.f, 0.f};

    for (int kt = 0; kt < 16; kt++) {  // key steps of 32
        const float* ap = Pp + (size_t)(q0 + lm) * 512 + kt * 32 + q4 * 8;
        float4 a0 = *(const float4*)ap;
        float4 a1 = *(const float4*)(ap + 4);
        bf16x8 af;
        af[0] = (bf16_t)a0.x; af[1] = (bf16_t)a0.y; af[2] = (bf16_t)a0.z; af[3] = (bf16_t)a0.w;
        af[4] = (bf16_t)a1.x; af[5] = (bf16_t)a1.y; af[6] = (bf16_t)a1.z; af[7] = (bf16_t)a1.w;
#pragma unroll
        for (int c = 0; c < 4; c++) {
            bf16x8 bf = *(const bf16x8*)&Vp[(size_t)(c * 16 + lm) * 512 + kt * 32 + q4 * 8];
            acc[c] = mfma16(af, bf, acc[c]);
        }
    }
    int b = bh >> 4, h = bh & 15;
#pragma unroll
    for (int c = 0; c < 4; c++)
#pragma unroll
        for (int i = 0; i < 4; i++) {
            int q = q0 + q4 * 4 + i;
            int d = c * 16 + lm;
            xo[((size_t)(b * 512 + q)) * 1024 + h * 64 + d] = (bf16_t)acc[c][i];
        }
}

// ---------- LayerNorm over last dim (1024) ----------
__global__ __launch_bounds__(256) void layernorm_kernel(const float* __restrict__ ypre,
                                                        const float* __restrict__ g,
                                                        const float* __restrict__ bvec,
                                                        float* __restrict__ out) {
    int row = blockIdx.x;
    int t = threadIdx.x;
    float4 v = ((const float4*)(ypre + (size_t)row * 1024))[t];
    float s = v.x + v.y + v.z + v.w;
    float sq = v.x * v.x + v.y * v.y + v.z * v.z + v.w * v.w;
#pragma unroll
    for (int off = 32; off; off >>= 1) {
        s += __shfl_down(s, off);
        sq += __shfl_down(sq, off);
    }
    __shared__ float ss[4], ssq[4];
    if ((t & 63) == 0) { ss[t >> 6] = s; ssq[t >> 6] = sq; }
    __syncthreads();
    float tot = ss[0] + ss[1] + ss[2] + ss[3];
    float totq = ssq[0] + ssq[1] + ssq[2] + ssq[3];
    float mu = tot * (1.0f / 1024.0f);
    float var = totq * (1.0f / 1024.0f) - mu * mu;
    float rstd = rsqrtf(var + 1e-5f);
    float4 gg = ((const float4*)g)[t];
    float4 bb = ((const float4*)bvec)[t];
    float4 o;
    o.x = (v.x - mu) * rstd * gg.x + bb.x;
    o.y = (v.y - mu) * rstd * gg.y + bb.y;
    o.z = (v.z - mu) * rstd * gg.z + bb.z;
    o.w = (v.w - mu) * rstd * gg.w + bb.w;
    ((float4*)(out + (size_t)row * 1024))[t] = o;
}

extern "C" void kernel_launch(void* const* d_in, const int* in_sizes, int n_in,
                              void* d_out, int out_size, void* d_ws, size_t ws_size,
                              hipStream_t stream) {
    const float* x         = (const float*)d_in[0];
    const float* Wq        = (const float*)d_in[1];
    const float* bq        = (const float*)d_in[2];
    const float* Wk        = (const float*)d_in[3];
    const float* bk        = (const float*)d_in[4];
    const float* Wv        = (const float*)d_in[5];
    const float* bv        = (const float*)d_in[6];
    const float* Wo        = (const float*)d_in[7];
    const float* bo        = (const float*)d_in[8];
    const float* ln_g      = (const float*)d_in[9];
    const float* ln_b      = (const float*)d_in[10];
    const float* help_vals = (const float*)d_in[11];
    const int*   help_mask = (const int*)d_in[12];
    const int*   attn_mask = (const int*)d_in[13];

    char* ws = (char*)d_ws;
    bf16_t* xb   = (bf16_t*)(ws);                       // 8 MB  [4096,1024]
    bf16_t* wqt  = (bf16_t*)(ws + ((size_t)8 << 20));   // 2 MB  [1024,1024] (N-major)
    bf16_t* wkt  = (bf16_t*)(ws + ((size_t)10 << 20));
    bf16_t* wvt  = (bf16_t*)(ws + ((size_t)12 << 20));
    bf16_t* wot  = (bf16_t*)(ws + ((size_t)14 << 20));
    bf16_t* qb   = (bf16_t*)(ws + ((size_t)16 << 20));  // 8 MB  [B,H,S,DK]
    bf16_t* kb   = (bf16_t*)(ws + ((size_t)24 << 20));  // 8 MB  [B,H,S,DK]
    bf16_t* vt   = (bf16_t*)(ws + ((size_t)32 << 20));  // 8 MB  [B,H,DK,S]
    bf16_t* xo   = (bf16_t*)(ws + ((size_t)40 << 20));  // 8 MB  [B,S,H*DK]
    float*  ypre = (float*)(ws + ((size_t)48 << 20));   // 16 MB [4096,1024]

    float* y_out = (float*)d_out;                      // [B,S,D] f32
    float* attn_out = y_out + (size_t)4096 * 1024;     // [B,H,S,S] f32

    cast_kernel<<<4096, 256, 0, stream>>>(x, xb);
    dim3 tg(32, 32);
    transpose_kernel<<<tg, 256, 0, stream>>>(Wq, wqt);
    transpose_kernel<<<tg, 256, 0, stream>>>(Wk, wkt);
    transpose_kernel<<<tg, 256, 0, stream>>>(Wv, wvt);
    transpose_kernel<<<tg, 256, 0, stream>>>(Wo, wot);

    dim3 gg(8, 32);  // N/128, M/128
    gemm_bt<0><<<gg, 256, 0, stream>>>(xb, wqt, bq, nullptr, qb);
    gemm_bt<0><<<gg, 256, 0, stream>>>(xb, wkt, bk, nullptr, kb);
    gemm_bt<2><<<gg, 256, 0, stream>>>(xb, wvt, bv, nullptr, vt);

    dim3 ga(8, 128);  // qtiles, B*H
    attn_kernel<<<ga, 256, 0, stream>>>(qb, kb, help_vals, help_mask, attn_mask, attn_out);
    pv_kernel<<<ga, 256, 0, stream>>>(attn_out, vt, xo);

    gemm_bt<3><<<gg, 256, 0, stream>>>(xo, wot, bo, x, ypre);
    layernorm_kernel<<<4096, 256, 0, stream>>>(ypre, ln_g, ln_b, y_out);
}

// Round 3
// 570.677 us; speedup vs baseline: 1.6309x; 1.6309x over previous
//
#include <hip/hip_runtime.h>
#include <hip/hip_bf16.h>

typedef __bf16 bf16_t;
typedef __bf16 bf16x4 __attribute__((ext_vector_type(4)));
typedef __bf16 bf16x8 __attribute__((ext_vector_type(8)));
typedef float f32x4 __attribute__((ext_vector_type(4)));

// Problem dims (fixed): B=8, S=512, D=1024, H=16, DK=64; M=B*S=4096, N=K=1024.

__device__ __forceinline__ f32x4 mfma16(bf16x8 a, bf16x8 b, f32x4 c) {
    return __builtin_amdgcn_mfma_f32_16x16x32_bf16(a, b, c, 0, 0, 0);
}

// ---------- prep: fp32 -> bf16 cast (x) ----------
__global__ __launch_bounds__(256) void cast_kernel(const float* __restrict__ x,
                                                   bf16_t* __restrict__ xb) {
    size_t i = ((size_t)blockIdx.x * 256 + threadIdx.x) * 4;
    float4 v = *(const float4*)(x + i);
    bf16x4 o;
    o[0] = (bf16_t)v.x; o[1] = (bf16_t)v.y; o[2] = (bf16_t)v.z; o[3] = (bf16_t)v.w;
    *(bf16x4*)(xb + i) = o;
}

// ---------- prep: W [K=1024][N=1024] f32 -> Wt [N][K] bf16 ----------
__global__ __launch_bounds__(256) void transpose_kernel(const float* __restrict__ W,
                                                        bf16_t* __restrict__ Wt) {
    __shared__ float tile[32][33];
    int tx = threadIdx.x & 31, ty = threadIdx.x >> 5;  // 32x8
    int bx = blockIdx.x * 32, by = blockIdx.y * 32;    // bx: n, by: k
#pragma unroll
    for (int j = 0; j < 4; j++)
        tile[ty + j * 8][tx] = W[(size_t)(by + ty + j * 8) * 1024 + bx + tx];
    __syncthreads();
#pragma unroll
    for (int j = 0; j < 4; j++)
        Wt[(size_t)(bx + ty + j * 8) * 1024 + by + tx] = (bf16_t)tile[tx][ty + j * 8];
}

// ---------- GEMM: C[m][n] = A[m][:] . Bt[n][:] + bias[n], various epilogues ----------
// MODE 0: write bf16 [B,H,S,DK]   (Q and K layouts)
// MODE 2: write bf16 [B,H,DK,S]   (V transposed for PV mfma B-fragments)
// MODE 3: write f32  [M,N] = v + resid[m][n]   (output proj + residual, pre-LN)
template <int MODE>
__global__ __launch_bounds__(256) void gemm_bt(const bf16_t* __restrict__ A,
                                               const bf16_t* __restrict__ Bt,
                                               const float* __restrict__ bias,
                                               const float* __restrict__ resid,
                                               void* __restrict__ outp) {
    constexpr int K = 1024, N = 1024;
    __shared__ bf16_t As[128][40];  // +8 pad: stride 80B = 20 banks -> 2-way (free)
    __shared__ bf16_t Bs[128][40];
    const int t = threadIdx.x;
    const int lane = t & 63;
    const int wv = t >> 6;
    const int lm = lane & 15, q4 = lane >> 4;
    const int mblk = blockIdx.y * 128, nblk = blockIdx.x * 128;
    const int mrow = (wv & 1) * 64, ncol = (wv >> 1) * 64;

    f32x4 acc[4][4];
#pragma unroll
    for (int r = 0; r < 4; r++)
#pragma unroll
        for (int c = 0; c < 4; c++) acc[r][c] = (f32x4){0.f, 0.f, 0.f, 0.f};

    for (int k0 = 0; k0 < K; k0 += 32) {
#pragma unroll
        for (int ld = 0; ld < 2; ld++) {
            int id = t + ld * 256;
            int r = id >> 2, c = (id & 3) * 8;
            *(bf16x8*)&As[r][c] = *(const bf16x8*)&A[(size_t)(mblk + r) * K + k0 + c];
            *(bf16x8*)&Bs[r][c] = *(const bf16x8*)&Bt[(size_t)(nblk + r) * K + k0 + c];
        }
        __syncthreads();
        bf16x8 af[4], bf[4];
#pragma unroll
        for (int r = 0; r < 4; r++) af[r] = *(const bf16x8*)&As[mrow + r * 16 + lm][q4 * 8];
#pragma unroll
        for (int c = 0; c < 4; c++) bf[c] = *(const bf16x8*)&Bs[ncol + c * 16 + lm][q4 * 8];
#pragma unroll
        for (int r = 0; r < 4; r++)
#pragma unroll
            for (int c = 0; c < 4; c++) acc[r][c] = mfma16(af[r], bf[c], acc[r][c]);
        __syncthreads();
    }

#pragma unroll
    for (int r = 0; r < 4; r++)
#pragma unroll
        for (int c = 0; c < 4; c++)
#pragma unroll
            for (int i = 0; i < 4; i++) {
                int m = mblk + mrow + r * 16 + q4 * 4 + i;
                int n = nblk + ncol + c * 16 + lm;
                float v = acc[r][c][i] + bias[n];
                if (MODE == 0) {
                    int b = m >> 9, s = m & 511, h = n >> 6, d = n & 63;
                    ((bf16_t*)outp)[(((size_t)(b * 16 + h) * 512) + s) * 64 + d] = (bf16_t)v;
                } else if (MODE == 2) {
                    int b = m >> 9, s = m & 511, h = n >> 6, d = n & 63;
                    ((bf16_t*)outp)[(((size_t)(b * 16 + h) * 64) + d) * 512 + s] = (bf16_t)v;
                } else {
                    ((float*)outp)[(size_t)m * N + n] = v + resid[(size_t)m * N + n];
                }
            }
}

// ---------- scores^T = K·Q^T /8, attn_mask, help blend, softmax -> attn [B,H,S,S] f32 ----
// Transposed MFMA (A=K rows -> D row=key, B=Q rows -> D col=q) so each lane holds
// 4 CONTIGUOUS keys of one q row: all help/mask/attn accesses become float4/int4.
// grid: (S/16=32, B*H=128); block 256 = 4 waves; wave wv owns keys [wv*128, wv*128+128)
__global__ __launch_bounds__(256) void attn_kernel(const bf16_t* __restrict__ Qb,
                                                   const bf16_t* __restrict__ Kb,
                                                   const float* __restrict__ help_vals,
                                                   const int* __restrict__ help_mask,
                                                   const int* __restrict__ attn_mask,
                                                   float* __restrict__ attn_out) {
    const int t = threadIdx.x;
    const int lane = t & 63, wv = t >> 6;
    const int lm = lane & 15, q4 = lane >> 4;
    const int bh = blockIdx.y;
    const int b = bh >> 4;
    const int q0 = blockIdx.x * 16;
    const bf16_t* Qp = Qb + (size_t)bh * 512 * 64;
    const bf16_t* Kp = Kb + (size_t)bh * 512 * 64;

    // B-fragment: Q rows (n = lm -> q), k = q4*8 + j, two 32-wide k halves
    const bf16x8 bq0 = *(const bf16x8*)&Qp[(size_t)(q0 + lm) * 64 + q4 * 8];
    const bf16x8 bq1 = *(const bf16x8*)&Qp[(size_t)(q0 + lm) * 64 + 32 + q4 * 8];

    f32x4 acc[8];
#pragma unroll
    for (int kt = 0; kt < 8; kt++) acc[kt] = (f32x4){0.f, 0.f, 0.f, 0.f};
#pragma unroll
    for (int kt = 0; kt < 8; kt++) {
        const int krow = wv * 128 + kt * 16 + lm;  // A: m = lm -> key
        bf16x8 ak0 = *(const bf16x8*)&Kp[(size_t)krow * 64 + q4 * 8];
        bf16x8 ak1 = *(const bf16x8*)&Kp[(size_t)krow * 64 + 32 + q4 * 8];
        acc[kt] = mfma16(ak0, bq0, acc[kt]);
        acc[kt] = mfma16(ak1, bq1, acc[kt]);
    }

    // lane holds: q = q0 + lm (fixed), keys = wv*128 + kt*16 + q4*4 + [0..3]
    const int q = q0 + lm;
    const size_t qrow = ((size_t)bh * 512 + q) * 512;
    const size_t arow = ((size_t)b * 512 + q) * 512;

    float mloc = -3e38f;
#pragma unroll
    for (int kt = 0; kt < 8; kt++) {
        const int keyb = wv * 128 + kt * 16 + q4 * 4;
        const float4 hv = *(const float4*)&help_vals[qrow + keyb];
        const int4 hm = *(const int4*)&help_mask[qrow + keyb];
        const int4 am = *(const int4*)&attn_mask[arow + keyb];
#pragma unroll
        for (int i = 0; i < 4; i++) {
            const int hmv = (i == 0) ? hm.x : (i == 1) ? hm.y : (i == 2) ? hm.z : hm.w;
            const int amv = (i == 0) ? am.x : (i == 1) ? am.y : (i == 2) ? am.z : am.w;
            const float hvv = (i == 0) ? hv.x : (i == 1) ? hv.y : (i == 2) ? hv.z : hv.w;
            float s = acc[kt][i] * 0.125f;
            s = amv ? -1e9f : s;
            s = hmv ? 0.5f * hvv + 0.5f * s : s;
            acc[kt][i] = s;
            mloc = fmaxf(mloc, s);
        }
    }
    // reduce max across q4 groups (lanes sharing lm): xor 16, 32
    mloc = fmaxf(mloc, __shfl_xor(mloc, 16));
    mloc = fmaxf(mloc, __shfl_xor(mloc, 32));

    __shared__ float wmax[4][16];
    __shared__ float wsum[4][16];
    if (q4 == 0) wmax[wv][lm] = mloc;
    __syncthreads();
    float gmax = fmaxf(fmaxf(wmax[0][lm], wmax[1][lm]), fmaxf(wmax[2][lm], wmax[3][lm]));

    float lsum = 0.f;
#pragma unroll
    for (int kt = 0; kt < 8; kt++)
#pragma unroll
        for (int i = 0; i < 4; i++) {
            float p = __expf(acc[kt][i] - gmax);
            acc[kt][i] = p;
            lsum += p;
        }
    lsum += __shfl_xor(lsum, 16);
    lsum += __shfl_xor(lsum, 32);
    if (q4 == 0) wsum[wv][lm] = lsum;
    __syncthreads();
    const float rinv = 1.0f / (wsum[0][lm] + wsum[1][lm] + wsum[2][lm] + wsum[3][lm]);

#pragma unroll
    for (int kt = 0; kt < 8; kt++) {
        const int keyb = wv * 128 + kt * 16 + q4 * 4;
        float4 o;
        o.x = acc[kt][0] * rinv;
        o.y = acc[kt][1] * rinv;
        o.z = acc[kt][2] * rinv;
        o.w = acc[kt][3] * rinv;
        *(float4*)&attn_out[qrow + keyb] = o;
    }
}

// ---------- ctx = attn @ V  -> xo [B,S,H*DK] bf16 ----------
__global__ __launch_bounds__(256) void pv_kernel(const float* __restrict__ attn,
                                                 const bf16_t* __restrict__ Vt,
                                                 bf16_t* __restrict__ xo) {
    const int t = threadIdx.x;
    const int lane = t & 63, wv = t >> 6;
    const int lm = lane & 15, q4 = lane >> 4;
    const int bh = blockIdx.y;
    const int q0 = blockIdx.x * 64 + wv * 16;
    const float* Pp = attn + (size_t)bh * 512 * 512;
    const bf16_t* Vp = Vt + (size_t)bh * 64 * 512;  // [dk][s]

    f32x4 acc[4];
#pragma unroll
    for (int c = 0; c < 4; c++) acc[c] = (f32x4){0.f, 0.f, 0.f, 0.f};

    for (int kt = 0; kt < 16; kt++) {  // key steps of 32
        const float* ap = Pp + (size_t)(q0 + lm) * 512 + kt * 32 + q4 * 8;
        float4 a0 = *(const float4*)ap;
        float4 a1 = *(const float4*)(ap + 4);
        bf16x8 af;
        af[0] = (bf16_t)a0.x; af[1] = (bf16_t)a0.y; af[2] = (bf16_t)a0.z; af[3] = (bf16_t)a0.w;
        af[4] = (bf16_t)a1.x; af[5] = (bf16_t)a1.y; af[6] = (bf16_t)a1.z; af[7] = (bf16_t)a1.w;
#pragma unroll
        for (int c = 0; c < 4; c++) {
            bf16x8 bf = *(const bf16x8*)&Vp[(size_t)(c * 16 + lm) * 512 + kt * 32 + q4 * 8];
            acc[c] = mfma16(af, bf, acc[c]);
        }
    }
    int b = bh >> 4, h = bh & 15;
#pragma unroll
    for (int c = 0; c < 4; c++)
#pragma unroll
        for (int i = 0; i < 4; i++) {
            int q = q0 + q4 * 4 + i;
            int d = c * 16 + lm;
            xo[((size_t)(b * 512 + q)) * 1024 + h * 64 + d] = (bf16_t)acc[c][i];
        }
}

// ---------- LayerNorm over last dim (1024) ----------
__global__ __launch_bounds__(256) void layernorm_kernel(const float* __restrict__ ypre,
                                                        const float* __restrict__ g,
                                                        const float* __restrict__ bvec,
                                                        float* __restrict__ out) {
    int row = blockIdx.x;
    int t = threadIdx.x;
    float4 v = ((const float4*)(ypre + (size_t)row * 1024))[t];
    float s = v.x + v.y + v.z + v.w;
    float sq = v.x * v.x + v.y * v.y + v.z * v.z + v.w * v.w;
#pragma unroll
    for (int off = 32; off; off >>= 1) {
        s += __shfl_down(s, off);
        sq += __shfl_down(sq, off);
    }
    __shared__ float ss[4], ssq[4];
    if ((t & 63) == 0) { ss[t >> 6] = s; ssq[t >> 6] = sq; }
    __syncthreads();
    float tot = ss[0] + ss[1] + ss[2] + ss[3];
    float totq = ssq[0] + ssq[1] + ssq[2] + ssq[3];
    float mu = tot * (1.0f / 1024.0f);
    float var = totq * (1.0f / 1024.0f) - mu * mu;
    float rstd = rsqrtf(var + 1e-5f);
    float4 gg = ((const float4*)g)[t];
    float4 bb = ((const float4*)bvec)[t];
    float4 o;
    o.x = (v.x - mu) * rstd * gg.x + bb.x;
    o.y = (v.y - mu) * rstd * gg.y + bb.y;
    o.z = (v.z - mu) * rstd * gg.z + bb.z;
    o.w = (v.w - mu) * rstd * gg.w + bb.w;
    ((float4*)(out + (size_t)row * 1024))[t] = o;
}

extern "C" void kernel_launch(void* const* d_in, const int* in_sizes, int n_in,
                              void* d_out, int out_size, void* d_ws, size_t ws_size,
                              hipStream_t stream) {
    const float* x         = (const float*)d_in[0];
    const float* Wq        = (const float*)d_in[1];
    const float* bq        = (const float*)d_in[2];
    const float* Wk        = (const float*)d_in[3];
    const float* bk        = (const float*)d_in[4];
    const float* Wv        = (const float*)d_in[5];
    const float* bv        = (const float*)d_in[6];
    const float* Wo        = (const float*)d_in[7];
    const float* bo        = (const float*)d_in[8];
    const float* ln_g      = (const float*)d_in[9];
    const float* ln_b      = (const float*)d_in[10];
    const float* help_vals = (const float*)d_in[11];
    const int*   help_mask = (const int*)d_in[12];
    const int*   attn_mask = (const int*)d_in[13];

    char* ws = (char*)d_ws;
    bf16_t* xb   = (bf16_t*)(ws);                       // 8 MB  [4096,1024]
    bf16_t* wqt  = (bf16_t*)(ws + ((size_t)8 << 20));   // 2 MB  [1024,1024] (N-major)
    bf16_t* wkt  = (bf16_t*)(ws + ((size_t)10 << 20));
    bf16_t* wvt  = (bf16_t*)(ws + ((size_t)12 << 20));
    bf16_t* wot  = (bf16_t*)(ws + ((size_t)14 << 20));
    bf16_t* qb   = (bf16_t*)(ws + ((size_t)16 << 20));  // 8 MB  [B,H,S,DK]
    bf16_t* kb   = (bf16_t*)(ws + ((size_t)24 << 20));  // 8 MB  [B,H,S,DK]
    bf16_t* vt   = (bf16_t*)(ws + ((size_t)32 << 20));  // 8 MB  [B,H,DK,S]
    bf16_t* xo   = (bf16_t*)(ws + ((size_t)40 << 20));  // 8 MB  [B,S,H*DK]
    float*  ypre = (float*)(ws + ((size_t)48 << 20));   // 16 MB [4096,1024]

    float* y_out = (float*)d_out;                      // [B,S,D] f32
    float* attn_out = y_out + (size_t)4096 * 1024;     // [B,H,S,S] f32

    cast_kernel<<<4096, 256, 0, stream>>>(x, xb);
    dim3 tg(32, 32);
    transpose_kernel<<<tg, 256, 0, stream>>>(Wq, wqt);
    transpose_kernel<<<tg, 256, 0, stream>>>(Wk, wkt);
    transpose_kernel<<<tg, 256, 0, stream>>>(Wv, wvt);
    transpose_kernel<<<tg, 256, 0, stream>>>(Wo, wot);

    dim3 gg(8, 32);  // N/128, M/128
    gemm_bt<0><<<gg, 256, 0, stream>>>(xb, wqt, bq, nullptr, qb);
    gemm_bt<0><<<gg, 256, 0, stream>>>(xb, wkt, bk, nullptr, kb);
    gemm_bt<2><<<gg, 256, 0, stream>>>(xb, wvt, bv, nullptr, vt);

    dim3 ga(32, 128);  // q tiles of 16, B*H
    attn_kernel<<<ga, 256, 0, stream>>>(qb, kb, help_vals, help_mask, attn_mask, attn_out);
    dim3 gp(8, 128);
    pv_kernel<<<gp, 256, 0, stream>>>(attn_out, vt, xo);

    gemm_bt<3><<<gg, 256, 0, stream>>>(xo, wot, bo, x, ypre);
    layernorm_kernel<<<4096, 256, 0, stream>>>(ypre, ln_g, ln_b, y_out);
}